// Round 1
// baseline (628.657 us; speedup 1.0000x reference)
//
#include <hip/hip_runtime.h>

#define B_ 512
#define N_ 256
#define H_ 6
#define HD_ 32
#define C_ 192
#define SCALE 0.17677669529663687f

typedef __attribute__((ext_vector_type(8))) short bf16x8;
typedef __attribute__((ext_vector_type(4))) float f32x4;
typedef __attribute__((ext_vector_type(4))) unsigned short u16x4;

__device__ __forceinline__ unsigned short f2bf(float x) {
    unsigned int u = __builtin_bit_cast(unsigned int, x);
    return (unsigned short)((u + 0x7fffu + ((u >> 16) & 1u)) >> 16);
}

// ---------------- prep: bias gather + W -> bf16 ----------------
__global__ __launch_bounds__(256) void prep_kernel(
    const int* __restrict__ rpi, const float* __restrict__ table,
    const float* __restrict__ W, float* __restrict__ bias,
    unsigned short* __restrict__ Wb)
{
    int t = blockIdx.x * 256 + threadIdx.x;
    if (t < N_ * N_) {
        int idx = rpi[t];
        #pragma unroll
        for (int h = 0; h < H_; ++h)
            bias[h * (N_ * N_) + t] = table[idx * H_ + h];
    } else {
        int i = t - N_ * N_;
        if (i < C_ * C_) Wb[i] = f2bf(W[i]);
    }
}

// ---------------- fused window attention ----------------
// block = (h, b), 256 threads = 4 waves; each wave does 16 q-rows per qt, qt=0..3
__global__ __launch_bounds__(256, 2) void attn_kernel(
    const float* __restrict__ qkv, const float* __restrict__ mask,
    const float* __restrict__ bias, unsigned short* __restrict__ xb)
{
    __shared__ unsigned short Kb[N_ * 40];       // K bf16, row stride 40 (80B)
    __shared__ unsigned short Vt[HD_ * 264];     // V transposed [d][k], stride 264 (528B)
    __shared__ unsigned short Pl[4][16 * 264];   // per-wave P bf16 [16 rows][256 cols]

    const int h = blockIdx.x;
    const int b = blockIdx.y;
    const int tid = threadIdx.x;
    const float* qkvb = qkv + (size_t)b * N_ * (3 * C_);

    // stage K and V (each row: 32 fp32 = 8 float4 chunks)
    #pragma unroll
    for (int it = 0; it < 8; ++it) {
        int idx = it * 256 + tid;          // 0..2047
        int row = idx >> 3, c4 = idx & 7;
        const float4 kf = *(const float4*)(qkvb + row * (3 * C_) + C_ + h * HD_ + c4 * 4);
        u16x4 kw;
        kw[0] = f2bf(kf.x); kw[1] = f2bf(kf.y); kw[2] = f2bf(kf.z); kw[3] = f2bf(kf.w);
        *(u16x4*)(&Kb[row * 40 + c4 * 4]) = kw;
        const float4 vf = *(const float4*)(qkvb + row * (3 * C_) + 2 * C_ + h * HD_ + c4 * 4);
        int d0 = c4 * 4;
        Vt[(d0 + 0) * 264 + row] = f2bf(vf.x);
        Vt[(d0 + 1) * 264 + row] = f2bf(vf.y);
        Vt[(d0 + 2) * 264 + row] = f2bf(vf.z);
        Vt[(d0 + 3) * 264 + row] = f2bf(vf.w);
    }
    __syncthreads();

    const int wv = tid >> 6;
    const int ln = tid & 63;
    const int lg = ln >> 4;
    const int lc = ln & 15;
    const float* maskp = mask + (size_t)(b & 63) * (N_ * N_);
    const float* biasp = bias + (size_t)h * (N_ * N_);
    unsigned short* pw = &Pl[wv][0];
    const f32x4 fz = {0.f, 0.f, 0.f, 0.f};

    for (int qt = 0; qt < 4; ++qt) {
        const int qbase = qt * 64 + wv * 16;

        // Q fragment: A[i][k], i = lc, k = 8*lg + j  (fp32 -> scaled bf16)
        const float* qp = qkvb + (size_t)(qbase + lc) * (3 * C_) + h * HD_ + 8 * lg;
        float4 q0 = *(const float4*)qp;
        float4 q1 = *(const float4*)(qp + 4);
        bf16x8 qa;
        qa[0] = (short)f2bf(q0.x * SCALE); qa[1] = (short)f2bf(q0.y * SCALE);
        qa[2] = (short)f2bf(q0.z * SCALE); qa[3] = (short)f2bf(q0.w * SCALE);
        qa[4] = (short)f2bf(q1.x * SCALE); qa[5] = (short)f2bf(q1.y * SCALE);
        qa[6] = (short)f2bf(q1.z * SCALE); qa[7] = (short)f2bf(q1.w * SCALE);

        // S = Q K^T : 16 N-tiles
        f32x4 acc[16];
        #pragma unroll
        for (int nt = 0; nt < 16; ++nt) {
            bf16x8 kb = *(const bf16x8*)(&Kb[(nt * 16 + lc) * 40 + lg * 8]);
            acc[nt] = __builtin_amdgcn_mfma_f32_16x16x32_bf16(qa, kb, fz, 0, 0, 0);
        }

        // + bias + mask, row max (row = qbase + lg*4 + r, col = nt*16 + lc)
        float rmax[4] = {-1e30f, -1e30f, -1e30f, -1e30f};
        #pragma unroll
        for (int nt = 0; nt < 16; ++nt) {
            const int col = nt * 16 + lc;
            const int rowb = (qbase + lg * 4) * N_ + col;
            #pragma unroll
            for (int r = 0; r < 4; ++r) {
                float v = acc[nt][r] + biasp[rowb + r * N_] + maskp[rowb + r * N_];
                acc[nt][r] = v;
                rmax[r] = fmaxf(rmax[r], v);
            }
        }
        #pragma unroll
        for (int r = 0; r < 4; ++r) {
            float m = rmax[r];
            m = fmaxf(m, __shfl_xor(m, 1));
            m = fmaxf(m, __shfl_xor(m, 2));
            m = fmaxf(m, __shfl_xor(m, 4));
            m = fmaxf(m, __shfl_xor(m, 8));
            rmax[r] = m;
        }
        float rsum[4] = {0.f, 0.f, 0.f, 0.f};
        #pragma unroll
        for (int nt = 0; nt < 16; ++nt) {
            #pragma unroll
            for (int r = 0; r < 4; ++r) {
                float e = __expf(acc[nt][r] - rmax[r]);
                acc[nt][r] = e;
                rsum[r] += e;
            }
        }
        #pragma unroll
        for (int r = 0; r < 4; ++r) {
            float s = rsum[r];
            s += __shfl_xor(s, 1);
            s += __shfl_xor(s, 2);
            s += __shfl_xor(s, 4);
            s += __shfl_xor(s, 8);
            rsum[r] = 1.0f / s;
        }

        // P -> bf16 into per-wave LDS (re-fragment for PV)
        #pragma unroll
        for (int nt = 0; nt < 16; ++nt) {
            #pragma unroll
            for (int r = 0; r < 4; ++r)
                pw[(lg * 4 + r) * 264 + nt * 16 + lc] = f2bf(acc[nt][r]);
        }

        // O = P V : A from Pl, B from Vt (contiguous in k)
        f32x4 o0 = fz, o1 = fz;
        #pragma unroll
        for (int s = 0; s < 8; ++s) {
            bf16x8 pa = *(const bf16x8*)(&pw[lc * 264 + s * 32 + lg * 8]);
            bf16x8 v0 = *(const bf16x8*)(&Vt[lc * 264 + s * 32 + lg * 8]);
            bf16x8 v1 = *(const bf16x8*)(&Vt[(16 + lc) * 264 + s * 32 + lg * 8]);
            o0 = __builtin_amdgcn_mfma_f32_16x16x32_bf16(pa, v0, o0, 0, 0, 0);
            o1 = __builtin_amdgcn_mfma_f32_16x16x32_bf16(pa, v1, o1, 0, 0, 0);
        }

        unsigned short* xo = xb + ((size_t)b * N_ + qbase + lg * 4) * C_ + h * HD_ + lc;
        #pragma unroll
        for (int r = 0; r < 4; ++r) {
            xo[r * C_ + 0]  = f2bf(o0[r] * rsum[r]);
            xo[r * C_ + 16] = f2bf(o1[r] * rsum[r]);
        }
    }
}

// ---------------- projection: out[M,192] = x[M,192] @ W^T + b ----------------
__global__ __launch_bounds__(256, 2) void proj_kernel(
    const unsigned short* __restrict__ xb, const unsigned short* __restrict__ Wb,
    const float* __restrict__ pb, float* __restrict__ out)
{
    const int tid = threadIdx.x;
    const int wv = tid >> 6, ln = tid & 63, lg = ln >> 4, lc = ln & 15;
    const size_t m0 = (size_t)blockIdx.x * 128 + wv * 32;

    f32x4 acc[2][12];
    #pragma unroll
    for (int a = 0; a < 2; ++a)
        #pragma unroll
        for (int nt = 0; nt < 12; ++nt) acc[a][nt] = (f32x4){0.f, 0.f, 0.f, 0.f};

    #pragma unroll
    for (int ks = 0; ks < 6; ++ks) {
        const int k0 = ks * 32 + lg * 8;
        bf16x8 a0 = *(const bf16x8*)(&xb[(m0 + lc) * C_ + k0]);
        bf16x8 a1 = *(const bf16x8*)(&xb[(m0 + 16 + lc) * C_ + k0]);
        #pragma unroll
        for (int nt = 0; nt < 12; ++nt) {
            bf16x8 bw = *(const bf16x8*)(&Wb[(nt * 16 + lc) * C_ + k0]);
            acc[0][nt] = __builtin_amdgcn_mfma_f32_16x16x32_bf16(a0, bw, acc[0][nt], 0, 0, 0);
            acc[1][nt] = __builtin_amdgcn_mfma_f32_16x16x32_bf16(a1, bw, acc[1][nt], 0, 0, 0);
        }
    }
    #pragma unroll
    for (int mt = 0; mt < 2; ++mt) {
        float* orow = out + (m0 + mt * 16 + lg * 4) * C_ + lc;
        #pragma unroll
        for (int nt = 0; nt < 12; ++nt) {
            float pbv = pb[nt * 16 + lc];
            #pragma unroll
            for (int r = 0; r < 4; ++r)
                orow[r * C_ + nt * 16] = acc[mt][nt][r] + pbv;
        }
    }
}

extern "C" void kernel_launch(void* const* d_in, const int* in_sizes, int n_in,
                              void* d_out, int out_size, void* d_ws, size_t ws_size,
                              hipStream_t stream)
{
    const float* qkv  = (const float*)d_in[0];
    const int*   rpi  = (const int*)d_in[1];
    const float* mask = (const float*)d_in[2];
    const float* tbl  = (const float*)d_in[3];
    const float* W    = (const float*)d_in[4];
    const float* pb   = (const float*)d_in[5];
    float* out = (float*)d_out;

    char* ws = (char*)d_ws;
    unsigned short* xb = (unsigned short*)ws;                              // 50331648 B
    float* bias        = (float*)(ws + 50331648);                          // 1572864 B
    unsigned short* Wb = (unsigned short*)(ws + 50331648 + 1572864);       // 73728 B

    prep_kernel<<<(N_ * N_ + C_ * C_) / 256, 256, 0, stream>>>(rpi, tbl, W, bias, Wb);
    attn_kernel<<<dim3(H_, B_), 256, 0, stream>>>(qkv, mask, bias, xb);
    proj_kernel<<<(B_ * N_) / 128, 256, 0, stream>>>(xb, Wb, pb, out);
}